// Round 3
// baseline (603.454 us; speedup 1.0000x reference)
//
#include <hip/hip_runtime.h>
#include <math.h>

#define IN_SIZE 128
#define E_SIZE  32
#define KDIM    160
#define THRESH  0.5f
#define BSHIFT  6                    // 64 nodes per bucket
#define BNODES  (1 << BSHIFT)

// ---------------- CSR construction ----------------

__global__ void k_hist(const int* __restrict__ dst, int* __restrict__ deg, int E) {
    int i = blockIdx.x * blockDim.x + threadIdx.x;
    if (i < E) atomicAdd(&deg[dst[i]], 1);
}

__global__ void k_blocksum(const int* __restrict__ deg, int* __restrict__ bsum, int N) {
    __shared__ int s[512];
    int i = blockIdx.x * 512 + threadIdx.x;
    s[threadIdx.x] = (i < N) ? deg[i] : 0;
    __syncthreads();
    for (int off = 256; off > 0; off >>= 1) {
        if (threadIdx.x < off) s[threadIdx.x] += s[threadIdx.x + off];
        __syncthreads();
    }
    if (threadIdx.x == 0) bsum[blockIdx.x] = s[0];
}

__global__ void k_scanbsum(const int* __restrict__ bsum, int* __restrict__ bscan,
                           int nb, int* __restrict__ offsets, int N) {
    if (blockIdx.x == 0 && threadIdx.x == 0) {
        int run = 0;
        for (int b = 0; b < nb; ++b) { bscan[b] = run; run += bsum[b]; }
        offsets[N] = run;   // == E
    }
}

__global__ void k_offsets(const int* __restrict__ deg, const int* __restrict__ bscan,
                          int* __restrict__ offsets, int N) {
    __shared__ int s[512];
    int tid = threadIdx.x;
    int i = blockIdx.x * 512 + tid;
    int v = (i < N) ? deg[i] : 0;
    s[tid] = v;
    __syncthreads();
    for (int off = 1; off < 512; off <<= 1) {       // Hillis-Steele inclusive scan
        int add = (tid >= off) ? s[tid - off] : 0;
        __syncthreads();
        s[tid] += add;
        __syncthreads();
    }
    if (i < N) offsets[i] = bscan[blockIdx.x] + s[tid] - v;   // exclusive
}

// bucket cursors start at each bucket's CSR base: offsets[64*b]
__global__ void k_binit(const int* __restrict__ offsets, int* __restrict__ bcur, int nbk, int N) {
    int b = blockIdx.x * blockDim.x + threadIdx.x;
    if (b < nbk) {
        int n0 = b << BSHIFT;
        bcur[b] = offsets[n0 < N ? n0 : N];
    }
}

// phase 1: append edge ids to their dst-bucket frontier (dense line writes)
__global__ void k_bin(const int* __restrict__ dst, int* __restrict__ bcur,
                      int* __restrict__ bin, int E) {
    int i = blockIdx.x * blockDim.x + threadIdx.x;
    if (i < E) {
        int b = dst[i] >> BSHIFT;
        int p = atomicAdd(&bcur[b], 1);
        bin[p] = i;
    }
}

// phase 2: one block per bucket; per-node cursors in LDS; writes stay in an ~8KB L2-local region
__global__ __launch_bounds__(256) void k_fill2(
    const int* __restrict__ dst, const int* __restrict__ offsets,
    const int* __restrict__ bin, int* __restrict__ eids, int N) {
    __shared__ int scur[BNODES];
    int b = blockIdx.x;
    int n0 = b << BSHIFT;
    int nend = n0 + BNODES; if (nend > N) nend = N;
    int tid = threadIdx.x;
    if (tid < BNODES && n0 + tid < N) scur[tid] = offsets[n0 + tid];
    __syncthreads();
    int bbase  = offsets[n0];
    int bbound = offsets[nend];
    for (int k = bbase + tid; k < bbound; k += 256) {
        int i = bin[k];
        int d = dst[i];
        int p = atomicAdd(&scur[d - n0], 1);
        eids[p] = i;
    }
}

// ---------------- per-node aggregate (1 wave / node, 8 edges x 8 float4-lanes) ----------------
// lane = es*8 + q : es = edge slot (0..7), q = feature quarter (owns features q*4..q*4+3).

__device__ __forceinline__ float red_q(float x) {        // sum across q (lane bits 0..2)
    x += __shfl_xor(x, 1); x += __shfl_xor(x, 2); x += __shfl_xor(x, 4);
    return x;
}
__device__ __forceinline__ float red_es(float x) {       // sum across es (lane bits 3..5)
    x += __shfl_xor(x, 8); x += __shfl_xor(x, 16); x += __shfl_xor(x, 32);
    return x;
}
__device__ __forceinline__ float4 red_es4(float4 v) {
    v.x = red_es(v.x); v.y = red_es(v.y); v.z = red_es(v.z); v.w = red_es(v.w);
    return v;
}

__global__ __launch_bounds__(256, 8) void k_node(
    const float* __restrict__ ef, const int* __restrict__ offsets,
    const int* __restrict__ eids, float* __restrict__ agg, int N)
{
    int wid = blockIdx.x * (blockDim.x >> 6) + (threadIdx.x >> 6);   // node id
    if (wid >= N) return;
    int lane = threadIdx.x & 63;
    int es = lane >> 3;
    int q  = lane & 7;
    int start = offsets[wid];
    int deg   = offsets[wid + 1] - start;

    // phase A: per-feature sum over in-edges
    float4 esum = make_float4(0.f, 0.f, 0.f, 0.f);
    for (int i = es; i < deg; i += 8) {
        int eid = eids[start + i];
        float4 f = *(const float4*)&ef[(size_t)eid * E_SIZE + q * 4];
        esum.x += f.x; esum.y += f.y; esum.z += f.z; esum.w += f.w;
    }
    esum = red_es4(esum);
    float inv = (deg > 0) ? 1.f / (float)deg : 0.f;
    float4 hk = make_float4(esum.x * inv, esum.y * inv, esum.z * inv, esum.w * inv);
    float hn2 = hk.x * hk.x + hk.y * hk.y + hk.z * hk.z + hk.w * hk.w;
    hn2 = red_q(hn2);                                   // ||hk||^2, all lanes
    float hnorm = sqrtf(hn2);

    // phase B: cosine-thresholded masked sums (ef rows re-read; L2/L3-hot)
    float4 ssum = make_float4(0.f, 0.f, 0.f, 0.f);
    float scnt = 0.f;
    for (int i = es; i < deg; i += 8) {
        int eid = eids[start + i];
        float4 f = *(const float4*)&ef[(size_t)eid * E_SIZE + q * 4];
        float num = hk.x * f.x + hk.y * f.y + hk.z * f.z + hk.w * f.w;
        float fn2 = f.x * f.x + f.y * f.y + f.z * f.z + f.w * f.w;
        num = red_q(num);
        fn2 = red_q(fn2);
        float cosv = num / (hnorm * sqrtf(fn2));        // NaN (0/0) -> excluded, matches jnp
        if (cosv < THRESH) {
            ssum.x += f.x; ssum.y += f.y; ssum.z += f.z; ssum.w += f.w;
            scnt += 1.f;
        }
    }
    ssum = red_es4(ssum);
    scnt = red_es(scnt);                                // each es-slot contributes once

    float4 a;
    if (scnt > 0.f) {
        float r = 1.f / scnt;
        a = make_float4(ssum.x * r, ssum.y * r, ssum.z * r, ssum.w * r);
    } else {
        a = hk;
    }
    if (es == 0) *(float4*)&agg[(size_t)wid * E_SIZE + q * 4] = a;
}

// ---------------- GEMM: out[N][128] = [h_in | agg] @ W^T ----------------
// BM=128, BN=128(all), BK=32; 256 threads; 8x8 acc per thread.

__global__ __launch_bounds__(256) void k_gemm(
    const float* __restrict__ A0,   // h_in [N][128]
    const float* __restrict__ A1,   // agg  [N][32]
    const float* __restrict__ W,    // [128][160]
    float* __restrict__ out, int N)
{
    __shared__ float As[128][33];   // +1 pad: a-reads conflict-free
    __shared__ float Bs[32][132];   // transposed W chunk; 132 keeps float4 rows 16B-aligned
    int t = threadIdx.x;
    int m0 = blockIdx.x * 128;
    int tn = t & 15, tm = t >> 4;
    float acc[8][8];
    #pragma unroll
    for (int r = 0; r < 8; ++r)
        #pragma unroll
        for (int c = 0; c < 8; ++c) acc[r][c] = 0.f;

    for (int chunk = 0; chunk < 5; ++chunk) {
        // stage A tile (rows m0..m0+127, k-cols chunk*32..+31)
        #pragma unroll
        for (int l = 0; l < 4; ++l) {
            int id = l * 256 + t;          // 0..1023 float4 slots
            int r = id >> 3;               // 0..127
            int qq = id & 7;               // float4 col within 32
            int m = m0 + r;
            float4 v = make_float4(0.f, 0.f, 0.f, 0.f);
            if (m < N) {
                if (chunk < 4) v = *(const float4*)&A0[(size_t)m * IN_SIZE + chunk * 32 + qq * 4];
                else           v = *(const float4*)&A1[(size_t)m * E_SIZE + qq * 4];
            }
            As[r][qq * 4 + 0] = v.x; As[r][qq * 4 + 1] = v.y;
            As[r][qq * 4 + 2] = v.z; As[r][qq * 4 + 3] = v.w;
        }
        // stage W chunk transposed: Bs[kk][h] = W[h][chunk*32+kk]
        {
            int h  = t >> 1;
            int kb = (t & 1) * 16;
            #pragma unroll
            for (int i2 = 0; i2 < 4; ++i2) {
                float4 v = *(const float4*)&W[(size_t)h * KDIM + chunk * 32 + kb + i2 * 4];
                int kkq = kb + i2 * 4;
                Bs[kkq + 0][h] = v.x; Bs[kkq + 1][h] = v.y;
                Bs[kkq + 2][h] = v.z; Bs[kkq + 3][h] = v.w;
            }
        }
        __syncthreads();
        #pragma unroll 4
        for (int kk = 0; kk < 32; ++kk) {
            float a[8], b[8];
            #pragma unroll
            for (int r = 0; r < 8; ++r) a[r] = As[tm * 8 + r][kk];
            float4 b0 = *(const float4*)&Bs[kk][tn * 8];
            float4 b1 = *(const float4*)&Bs[kk][tn * 8 + 4];
            b[0] = b0.x; b[1] = b0.y; b[2] = b0.z; b[3] = b0.w;
            b[4] = b1.x; b[5] = b1.y; b[6] = b1.z; b[7] = b1.w;
            #pragma unroll
            for (int r = 0; r < 8; ++r)
                #pragma unroll
                for (int c = 0; c < 8; ++c)
                    acc[r][c] = fmaf(a[r], b[c], acc[r][c]);
        }
        __syncthreads();
    }
    #pragma unroll
    for (int r = 0; r < 8; ++r) {
        int m = m0 + tm * 8 + r;
        if (m < N) {
            float4 o0 = make_float4(acc[r][0], acc[r][1], acc[r][2], acc[r][3]);
            float4 o1 = make_float4(acc[r][4], acc[r][5], acc[r][6], acc[r][7]);
            *(float4*)&out[(size_t)m * IN_SIZE + tn * 8]     = o0;
            *(float4*)&out[(size_t)m * IN_SIZE + tn * 8 + 4] = o1;
        }
    }
}

// ---------------- launch ----------------

extern "C" void kernel_launch(void* const* d_in, const int* in_sizes, int n_in,
                              void* d_out, int out_size, void* d_ws, size_t ws_size,
                              hipStream_t stream) {
    const float* h_in = (const float*)d_in[0];
    const float* ef   = (const float*)d_in[1];
    const int*   dst  = (const int*)d_in[2];
    const float* W    = (const float*)d_in[3];
    float* out = (float*)d_out;
    int N = in_sizes[0] / IN_SIZE;     // 50000
    int E = in_sizes[2];               // 1600000
    int nbk = (N + BNODES - 1) >> BSHIFT;   // 782 buckets

    // workspace carve-out (256B aligned), ~20 MB total
    char* p = (char*)d_ws;
    auto take = [&](size_t bytes) { char* r = p; p += (bytes + 255) & ~(size_t)255; return r; };
    int*   deg     = (int*)take((size_t)N * 4);
    int*   offsets = (int*)take((size_t)(N + 1) * 4);
    int nb = (N + 511) / 512;
    int*   bsum    = (int*)take((size_t)nb * 4);
    int*   bscan   = (int*)take((size_t)nb * 4);
    int*   bcur    = (int*)take((size_t)nbk * 4);
    int*   binb    = (int*)take((size_t)E * 4);
    int*   eidsb   = (int*)take((size_t)E * 4);
    float* agg     = (float*)take((size_t)N * E_SIZE * 4);

    hipMemsetAsync(deg, 0, (size_t)N * 4, stream);
    k_hist    <<<(E + 255) / 256, 256, 0, stream>>>(dst, deg, E);
    k_blocksum<<<nb, 512, 0, stream>>>(deg, bsum, N);
    k_scanbsum<<<1, 64, 0, stream>>>(bsum, bscan, nb, offsets, N);
    k_offsets <<<nb, 512, 0, stream>>>(deg, bscan, offsets, N);
    k_binit   <<<(nbk + 255) / 256, 256, 0, stream>>>(offsets, bcur, nbk, N);
    k_bin     <<<(E + 255) / 256, 256, 0, stream>>>(dst, bcur, binb, E);
    k_fill2   <<<nbk, 256, 0, stream>>>(dst, offsets, binb, eidsb, N);
    k_node    <<<(N + 3) / 4, 256, 0, stream>>>(ef, offsets, eidsb, agg, N);
    k_gemm    <<<(N + 127) / 128, 256, 0, stream>>>(h_in, agg, W, out, N);
}

// Round 4
// 171.404 us; speedup vs baseline: 3.5207x; 3.5207x over previous
//
#include <hip/hip_runtime.h>
#include <math.h>

#define IN_SIZE 128
#define E_SIZE  32
#define KDIM    160
#define THRESH  0.5f
#define BSHIFT  6                    // 64 nodes per bucket
#define BNODES  (1 << BSHIFT)
#define NBK_MAX 1024                 // nbk = ceil(50000/64) = 782 <= 1024
#define NBIN_BLOCKS 256

// ---------------- bucket histogram (block-aggregated) ----------------

__global__ __launch_bounds__(256) void k_bhist(
    const int* __restrict__ dst, int* __restrict__ bktcnt, int E, int nbk)
{
    __shared__ int hist[NBK_MAX];
    int tid = threadIdx.x;
    for (int b = tid; b < nbk; b += 256) hist[b] = 0;
    __syncthreads();
    int chunk = (E + gridDim.x - 1) / gridDim.x;
    int s = blockIdx.x * chunk;
    int e = s + chunk; if (e > E) e = E;
    for (int i = s + tid; i < e; i += 256)
        atomicAdd(&hist[dst[i] >> BSHIFT], 1);
    __syncthreads();
    for (int b = tid; b < nbk; b += 256)
        if (hist[b]) atomicAdd(&bktcnt[b], hist[b]);
}

// ---------------- scan bucket totals -> bases + cursors ----------------

__global__ __launch_bounds__(1024) void k_bscan(
    const int* __restrict__ bktcnt, int* __restrict__ bktbase, int* __restrict__ bcur,
    int nbk, int* __restrict__ offsets, int N, int E)
{
    __shared__ int s[1024];
    int tid = threadIdx.x;
    int v = (tid < nbk) ? bktcnt[tid] : 0;
    s[tid] = v;
    __syncthreads();
    for (int off = 1; off < 1024; off <<= 1) {
        int add = (tid >= off) ? s[tid - off] : 0;
        __syncthreads();
        s[tid] += add;
        __syncthreads();
    }
    if (tid < nbk) {
        int base = s[tid] - v;          // exclusive
        bktbase[tid] = base;
        bcur[tid]    = base;
    }
    if (tid == 0) { bktbase[nbk] = E; offsets[N] = E; }
}

// ---------------- binning: block-aggregated counting sort ----------------
// bin entry packs (edge_id << 6) | (dst & 63); eid < 2^21 so it fits in 27 bits.

__global__ __launch_bounds__(256) void k_bin_agg(
    const int* __restrict__ dst, int* __restrict__ bcur,
    int* __restrict__ bin, int E, int nbk)
{
    __shared__ int hist[NBK_MAX];
    __shared__ int base[NBK_MAX];
    int tid = threadIdx.x;
    for (int b = tid; b < nbk; b += 256) hist[b] = 0;
    __syncthreads();
    int chunk = (E + gridDim.x - 1) / gridDim.x;
    int s = blockIdx.x * chunk;
    int e = s + chunk; if (e > E) e = E;
    for (int i = s + tid; i < e; i += 256)
        atomicAdd(&hist[dst[i] >> BSHIFT], 1);
    __syncthreads();
    for (int b = tid; b < nbk; b += 256) {
        int c = hist[b];
        base[b] = c ? atomicAdd(&bcur[b], c) : 0;   // reserve a contiguous run
        hist[b] = 0;                                // reuse as local cursor
    }
    __syncthreads();
    for (int i = s + tid; i < e; i += 256) {
        int d = dst[i];
        int b = d >> BSHIFT;
        int p = base[b] + atomicAdd(&hist[b], 1);
        bin[p] = (i << BSHIFT) | (d & (BNODES - 1));
    }
}

// ---------------- per-bucket exact placement + offsets ----------------
// one block per bucket; per-node counts/cursors in LDS; writes stay in one ~8KB region.

__global__ __launch_bounds__(256) void k_fill3(
    const int* __restrict__ bktbase, const int* __restrict__ bin,
    int* __restrict__ eids, int* __restrict__ offsets, int N)
{
    __shared__ int cnt[BNODES];
    __shared__ int nb0[BNODES];
    int b = blockIdx.x;
    int n0 = b << BSHIFT;
    int tid = threadIdx.x;
    int s = bktbase[b];
    int e = bktbase[b + 1];
    if (tid < BNODES) cnt[tid] = 0;
    __syncthreads();
    for (int k = s + tid; k < e; k += 256)
        atomicAdd(&cnt[bin[k] & (BNODES - 1)], 1);
    __syncthreads();
    if (tid < BNODES) {                         // wave 0: shuffle scan of 64 degs
        int v = cnt[tid];
        int x = v;
        #pragma unroll
        for (int off = 1; off < 64; off <<= 1) {
            int y = __shfl_up(x, off);
            if (tid >= off) x += y;
        }
        int nodebase = s + x - v;               // exclusive
        nb0[tid] = nodebase;
        if (n0 + tid < N) offsets[n0 + tid] = nodebase;
        cnt[tid] = 0;                           // reuse as cursor
    }
    __syncthreads();
    for (int k = s + tid; k < e; k += 256) {
        int pk = bin[k];
        int ln = pk & (BNODES - 1);
        int p = nb0[ln] + atomicAdd(&cnt[ln], 1);
        eids[p] = pk >> BSHIFT;
    }
}

// ---------------- per-node aggregate (1 wave / node, 8 edges x 8 float4-lanes) ----------------
// lane = es*8 + q : es = edge slot (0..7), q = feature quarter (owns features q*4..q*4+3).

__device__ __forceinline__ float red_q(float x) {        // sum across q (lane bits 0..2)
    x += __shfl_xor(x, 1); x += __shfl_xor(x, 2); x += __shfl_xor(x, 4);
    return x;
}
__device__ __forceinline__ float red_es(float x) {       // sum across es (lane bits 3..5)
    x += __shfl_xor(x, 8); x += __shfl_xor(x, 16); x += __shfl_xor(x, 32);
    return x;
}
__device__ __forceinline__ float4 red_es4(float4 v) {
    v.x = red_es(v.x); v.y = red_es(v.y); v.z = red_es(v.z); v.w = red_es(v.w);
    return v;
}

__global__ __launch_bounds__(256, 8) void k_node(
    const float* __restrict__ ef, const int* __restrict__ offsets,
    const int* __restrict__ eids, float* __restrict__ agg, int N)
{
    int wid = blockIdx.x * (blockDim.x >> 6) + (threadIdx.x >> 6);   // node id
    if (wid >= N) return;
    int lane = threadIdx.x & 63;
    int es = lane >> 3;
    int q  = lane & 7;
    int start = offsets[wid];
    int deg   = offsets[wid + 1] - start;

    // phase A: per-feature sum over in-edges
    float4 esum = make_float4(0.f, 0.f, 0.f, 0.f);
    for (int i = es; i < deg; i += 8) {
        int eid = eids[start + i];
        float4 f = *(const float4*)&ef[(size_t)eid * E_SIZE + q * 4];
        esum.x += f.x; esum.y += f.y; esum.z += f.z; esum.w += f.w;
    }
    esum = red_es4(esum);
    float inv = (deg > 0) ? 1.f / (float)deg : 0.f;
    float4 hk = make_float4(esum.x * inv, esum.y * inv, esum.z * inv, esum.w * inv);
    float hn2 = hk.x * hk.x + hk.y * hk.y + hk.z * hk.z + hk.w * hk.w;
    hn2 = red_q(hn2);                                   // ||hk||^2, all lanes
    float hnorm = sqrtf(hn2);

    // phase B: cosine-thresholded masked sums (ef rows re-read; L2/L3-hot)
    float4 ssum = make_float4(0.f, 0.f, 0.f, 0.f);
    float scnt = 0.f;
    for (int i = es; i < deg; i += 8) {
        int eid = eids[start + i];
        float4 f = *(const float4*)&ef[(size_t)eid * E_SIZE + q * 4];
        float num = hk.x * f.x + hk.y * f.y + hk.z * f.z + hk.w * f.w;
        float fn2 = f.x * f.x + f.y * f.y + f.z * f.z + f.w * f.w;
        num = red_q(num);
        fn2 = red_q(fn2);
        float cosv = num / (hnorm * sqrtf(fn2));        // NaN (0/0) -> excluded, matches jnp
        if (cosv < THRESH) {
            ssum.x += f.x; ssum.y += f.y; ssum.z += f.z; ssum.w += f.w;
            scnt += 1.f;
        }
    }
    ssum = red_es4(ssum);
    scnt = red_es(scnt);                                // each es-slot contributes once

    float4 a;
    if (scnt > 0.f) {
        float r = 1.f / scnt;
        a = make_float4(ssum.x * r, ssum.y * r, ssum.z * r, ssum.w * r);
    } else {
        a = hk;
    }
    if (es == 0) *(float4*)&agg[(size_t)wid * E_SIZE + q * 4] = a;
}

// ---------------- GEMM: out[N][128] = [h_in | agg] @ W^T ----------------
// BM=128, BN=128(all), BK=32; 256 threads; 8x8 acc per thread.

__global__ __launch_bounds__(256) void k_gemm(
    const float* __restrict__ A0,   // h_in [N][128]
    const float* __restrict__ A1,   // agg  [N][32]
    const float* __restrict__ W,    // [128][160]
    float* __restrict__ out, int N)
{
    __shared__ float As[128][33];   // +1 pad: a-reads conflict-free
    __shared__ float Bs[32][132];   // transposed W chunk; 132 keeps float4 rows 16B-aligned
    int t = threadIdx.x;
    int m0 = blockIdx.x * 128;
    int tn = t & 15, tm = t >> 4;
    float acc[8][8];
    #pragma unroll
    for (int r = 0; r < 8; ++r)
        #pragma unroll
        for (int c = 0; c < 8; ++c) acc[r][c] = 0.f;

    for (int chunk = 0; chunk < 5; ++chunk) {
        // stage A tile (rows m0..m0+127, k-cols chunk*32..+31)
        #pragma unroll
        for (int l = 0; l < 4; ++l) {
            int id = l * 256 + t;          // 0..1023 float4 slots
            int r = id >> 3;               // 0..127
            int qq = id & 7;               // float4 col within 32
            int m = m0 + r;
            float4 v = make_float4(0.f, 0.f, 0.f, 0.f);
            if (m < N) {
                if (chunk < 4) v = *(const float4*)&A0[(size_t)m * IN_SIZE + chunk * 32 + qq * 4];
                else           v = *(const float4*)&A1[(size_t)m * E_SIZE + qq * 4];
            }
            As[r][qq * 4 + 0] = v.x; As[r][qq * 4 + 1] = v.y;
            As[r][qq * 4 + 2] = v.z; As[r][qq * 4 + 3] = v.w;
        }
        // stage W chunk transposed: Bs[kk][h] = W[h][chunk*32+kk]
        {
            int h  = t >> 1;
            int kb = (t & 1) * 16;
            #pragma unroll
            for (int i2 = 0; i2 < 4; ++i2) {
                float4 v = *(const float4*)&W[(size_t)h * KDIM + chunk * 32 + kb + i2 * 4];
                int kkq = kb + i2 * 4;
                Bs[kkq + 0][h] = v.x; Bs[kkq + 1][h] = v.y;
                Bs[kkq + 2][h] = v.z; Bs[kkq + 3][h] = v.w;
            }
        }
        __syncthreads();
        #pragma unroll 4
        for (int kk = 0; kk < 32; ++kk) {
            float a[8], b[8];
            #pragma unroll
            for (int r = 0; r < 8; ++r) a[r] = As[tm * 8 + r][kk];
            float4 b0 = *(const float4*)&Bs[kk][tn * 8];
            float4 b1 = *(const float4*)&Bs[kk][tn * 8 + 4];
            b[0] = b0.x; b[1] = b0.y; b[2] = b0.z; b[3] = b0.w;
            b[4] = b1.x; b[5] = b1.y; b[6] = b1.z; b[7] = b1.w;
            #pragma unroll
            for (int r = 0; r < 8; ++r)
                #pragma unroll
                for (int c = 0; c < 8; ++c)
                    acc[r][c] = fmaf(a[r], b[c], acc[r][c]);
        }
        __syncthreads();
    }
    #pragma unroll
    for (int r = 0; r < 8; ++r) {
        int m = m0 + tm * 8 + r;
        if (m < N) {
            float4 o0 = make_float4(acc[r][0], acc[r][1], acc[r][2], acc[r][3]);
            float4 o1 = make_float4(acc[r][4], acc[r][5], acc[r][6], acc[r][7]);
            *(float4*)&out[(size_t)m * IN_SIZE + tn * 8]     = o0;
            *(float4*)&out[(size_t)m * IN_SIZE + tn * 8 + 4] = o1;
        }
    }
}

// ---------------- launch ----------------

extern "C" void kernel_launch(void* const* d_in, const int* in_sizes, int n_in,
                              void* d_out, int out_size, void* d_ws, size_t ws_size,
                              hipStream_t stream) {
    const float* h_in = (const float*)d_in[0];
    const float* ef   = (const float*)d_in[1];
    const int*   dst  = (const int*)d_in[2];
    const float* W    = (const float*)d_in[3];
    float* out = (float*)d_out;
    int N = in_sizes[0] / IN_SIZE;     // 50000
    int E = in_sizes[2];               // 1600000
    int nbk = (N + BNODES - 1) >> BSHIFT;   // 782 buckets (<= NBK_MAX)

    // workspace carve-out (256B aligned)
    char* p = (char*)d_ws;
    auto take = [&](size_t bytes) { char* r = p; p += (bytes + 255) & ~(size_t)255; return r; };
    int*   offsets = (int*)take((size_t)(N + 1) * 4);
    int*   bktcnt  = (int*)take((size_t)nbk * 4);
    int*   bktbase = (int*)take((size_t)(nbk + 1) * 4);
    int*   bcur    = (int*)take((size_t)nbk * 4);
    int*   binb    = (int*)take((size_t)E * 4);
    int*   eidsb   = (int*)take((size_t)E * 4);
    float* agg     = (float*)take((size_t)N * E_SIZE * 4);

    hipMemsetAsync(bktcnt, 0, (size_t)nbk * 4, stream);
    k_bhist  <<<NBIN_BLOCKS, 256, 0, stream>>>(dst, bktcnt, E, nbk);
    k_bscan  <<<1, 1024, 0, stream>>>(bktcnt, bktbase, bcur, nbk, offsets, N, E);
    k_bin_agg<<<NBIN_BLOCKS, 256, 0, stream>>>(dst, bcur, binb, E, nbk);
    k_fill3  <<<nbk, 256, 0, stream>>>(bktbase, binb, eidsb, offsets, N);
    k_node   <<<(N + 3) / 4, 256, 0, stream>>>(ef, offsets, eidsb, agg, N);
    k_gemm   <<<(N + 127) / 128, 256, 0, stream>>>(h_in, agg, W, out, N);
}

// Round 5
// 150.605 us; speedup vs baseline: 4.0069x; 1.1381x over previous
//
#include <hip/hip_runtime.h>
#include <math.h>

#define IN_SIZE 128
#define E_SIZE  32
#define KDIM    160
#define THRESH  0.5f
#define BSHIFT  6                    // 64 nodes per bucket
#define BNODES  (1 << BSHIFT)
#define NBK_MAX 1024                 // nbk = ceil(50000/64) = 782 <= 1024
#define NBIN_BLOCKS 256

// ---------------- bucket histogram (block-aggregated) ----------------

__global__ __launch_bounds__(256) void k_bhist(
    const int* __restrict__ dst, int* __restrict__ bktcnt, int E, int nbk)
{
    __shared__ int hist[NBK_MAX];
    int tid = threadIdx.x;
    for (int b = tid; b < nbk; b += 256) hist[b] = 0;
    __syncthreads();
    int chunk = (E + gridDim.x - 1) / gridDim.x;
    int s = blockIdx.x * chunk;
    int e = s + chunk; if (e > E) e = E;
    for (int i = s + tid; i < e; i += 256)
        atomicAdd(&hist[dst[i] >> BSHIFT], 1);
    __syncthreads();
    for (int b = tid; b < nbk; b += 256)
        if (hist[b]) atomicAdd(&bktcnt[b], hist[b]);
}

// ---------------- scan bucket totals -> bases + cursors ----------------

__global__ __launch_bounds__(1024) void k_bscan(
    const int* __restrict__ bktcnt, int* __restrict__ bktbase, int* __restrict__ bcur,
    int nbk, int* __restrict__ offsets, int N, int E)
{
    __shared__ int s[1024];
    int tid = threadIdx.x;
    int v = (tid < nbk) ? bktcnt[tid] : 0;
    s[tid] = v;
    __syncthreads();
    for (int off = 1; off < 1024; off <<= 1) {
        int add = (tid >= off) ? s[tid - off] : 0;
        __syncthreads();
        s[tid] += add;
        __syncthreads();
    }
    if (tid < nbk) {
        int base = s[tid] - v;          // exclusive
        bktbase[tid] = base;
        bcur[tid]    = base;
    }
    if (tid == 0) { bktbase[nbk] = E; offsets[N] = E; }
}

// ---------------- binning: block-aggregated counting sort ----------------
// bin entry packs (edge_id << 6) | (dst & 63); eid < 2^21 so it fits in 27 bits.

__global__ __launch_bounds__(256) void k_bin_agg(
    const int* __restrict__ dst, int* __restrict__ bcur,
    int* __restrict__ bin, int E, int nbk)
{
    __shared__ int hist[NBK_MAX];
    __shared__ int base[NBK_MAX];
    int tid = threadIdx.x;
    for (int b = tid; b < nbk; b += 256) hist[b] = 0;
    __syncthreads();
    int chunk = (E + gridDim.x - 1) / gridDim.x;
    int s = blockIdx.x * chunk;
    int e = s + chunk; if (e > E) e = E;
    for (int i = s + tid; i < e; i += 256)
        atomicAdd(&hist[dst[i] >> BSHIFT], 1);
    __syncthreads();
    for (int b = tid; b < nbk; b += 256) {
        int c = hist[b];
        base[b] = c ? atomicAdd(&bcur[b], c) : 0;   // reserve a contiguous run
        hist[b] = 0;                                // reuse as local cursor
    }
    __syncthreads();
    for (int i = s + tid; i < e; i += 256) {
        int d = dst[i];
        int b = d >> BSHIFT;
        int p = base[b] + atomicAdd(&hist[b], 1);
        bin[p] = (i << BSHIFT) | (d & (BNODES - 1));
    }
}

// ---------------- per-bucket exact placement + offsets ----------------
// one block per bucket; per-node counts/cursors in LDS; writes stay in one ~8KB region.

__global__ __launch_bounds__(256) void k_fill3(
    const int* __restrict__ bktbase, const int* __restrict__ bin,
    int* __restrict__ eids, int* __restrict__ offsets, int N)
{
    __shared__ int cnt[BNODES];
    __shared__ int nb0[BNODES];
    int b = blockIdx.x;
    int n0 = b << BSHIFT;
    int tid = threadIdx.x;
    int s = bktbase[b];
    int e = bktbase[b + 1];
    if (tid < BNODES) cnt[tid] = 0;
    __syncthreads();
    for (int k = s + tid; k < e; k += 256)
        atomicAdd(&cnt[bin[k] & (BNODES - 1)], 1);
    __syncthreads();
    if (tid < BNODES) {                         // wave 0: shuffle scan of 64 degs
        int v = cnt[tid];
        int x = v;
        #pragma unroll
        for (int off = 1; off < 64; off <<= 1) {
            int y = __shfl_up(x, off);
            if (tid >= off) x += y;
        }
        int nodebase = s + x - v;               // exclusive
        nb0[tid] = nodebase;
        if (n0 + tid < N) offsets[n0 + tid] = nodebase;
        cnt[tid] = 0;                           // reuse as cursor
    }
    __syncthreads();
    for (int k = s + tid; k < e; k += 256) {
        int pk = bin[k];
        int ln = pk & (BNODES - 1);
        int p = nb0[ln] + atomicAdd(&cnt[ln], 1);
        eids[p] = pk >> BSHIFT;
    }
}

// ---------------- per-node aggregate (1 wave / node, 8 edges x 8 float4-lanes) ----------------
// lane = es*8 + q : es = edge slot (0..7), q = feature quarter (owns features q*4..q*4+3).
// Edge rows register-cached across both phases (covers deg<=64; dynamic overflow loop beyond).

__device__ __forceinline__ float red_q(float x) {        // sum across q (lane bits 0..2)
    x += __shfl_xor(x, 1); x += __shfl_xor(x, 2); x += __shfl_xor(x, 4);
    return x;
}
__device__ __forceinline__ float red_es(float x) {       // sum across es (lane bits 3..5)
    x += __shfl_xor(x, 8); x += __shfl_xor(x, 16); x += __shfl_xor(x, 32);
    return x;
}
__device__ __forceinline__ float4 red_es4(float4 v) {
    v.x = red_es(v.x); v.y = red_es(v.y); v.z = red_es(v.z); v.w = red_es(v.w);
    return v;
}

__global__ __launch_bounds__(256, 4) void k_node(
    const float* __restrict__ ef, const int* __restrict__ offsets,
    const int* __restrict__ eids, float* __restrict__ agg, int N)
{
    int wid = blockIdx.x * (blockDim.x >> 6) + (threadIdx.x >> 6);   // node id
    if (wid >= N) return;
    int lane = threadIdx.x & 63;
    int es = lane >> 3;
    int q  = lane & 7;
    int start = offsets[wid];
    int deg   = offsets[wid + 1] - start;

    // preload up to 8 edge rows per slot into registers (static indices — stays in VGPRs)
    float4 fc[8];
    #pragma unroll
    for (int it = 0; it < 8; ++it) {
        int i = es + it * 8;
        float4 f = make_float4(0.f, 0.f, 0.f, 0.f);
        if (i < deg) {                      // uniform within each 8-lane q-group
            int eid = eids[start + i];
            f = *(const float4*)&ef[(size_t)eid * E_SIZE + q * 4];
        }
        fc[it] = f;
    }

    // phase A: per-feature sum over in-edges
    float4 esum = make_float4(0.f, 0.f, 0.f, 0.f);
    #pragma unroll
    for (int it = 0; it < 8; ++it) {
        esum.x += fc[it].x; esum.y += fc[it].y; esum.z += fc[it].z; esum.w += fc[it].w;
    }
    for (int i = es + 64; i < deg; i += 8) {            // overflow (deg>64): ~never
        int eid = eids[start + i];
        float4 f = *(const float4*)&ef[(size_t)eid * E_SIZE + q * 4];
        esum.x += f.x; esum.y += f.y; esum.z += f.z; esum.w += f.w;
    }
    esum = red_es4(esum);
    float inv = (deg > 0) ? 1.f / (float)deg : 0.f;
    float4 hk = make_float4(esum.x * inv, esum.y * inv, esum.z * inv, esum.w * inv);
    float hn2 = hk.x * hk.x + hk.y * hk.y + hk.z * hk.z + hk.w * hk.w;
    hn2 = red_q(hn2);                                   // ||hk||^2, all lanes
    float t2h = 0.25f * hn2;                            // THRESH^2 * ||hk||^2

    // phase B: cos < 0.5  <=>  num < 0  ||  num^2 < 0.25*hn2*fn2   (sqrt/div-free;
    // num=fn2=0 (inactive slot / zero row) -> excluded, matching jnp's NaN semantics)
    float4 ssum = make_float4(0.f, 0.f, 0.f, 0.f);
    float scnt = 0.f;
    #pragma unroll
    for (int it = 0; it < 8; ++it) {
        float4 f = fc[it];
        float num = hk.x * f.x + hk.y * f.y + hk.z * f.z + hk.w * f.w;
        float fn2 = f.x * f.x + f.y * f.y + f.z * f.z + f.w * f.w;
        num = red_q(num);
        fn2 = red_q(fn2);
        if (num < 0.f || num * num < t2h * fn2) {
            ssum.x += f.x; ssum.y += f.y; ssum.z += f.z; ssum.w += f.w;
            scnt += (es + it * 8 < deg) ? 1.f : 0.f;    // count real edges only (f=0 adds 0 to ssum)
        }
    }
    for (int i = es + 64; i < deg; i += 8) {            // overflow (deg>64): ~never
        int eid = eids[start + i];
        float4 f = *(const float4*)&ef[(size_t)eid * E_SIZE + q * 4];
        float num = hk.x * f.x + hk.y * f.y + hk.z * f.z + hk.w * f.w;
        float fn2 = f.x * f.x + f.y * f.y + f.z * f.z + f.w * f.w;
        num = red_q(num);
        fn2 = red_q(fn2);
        if (num < 0.f || num * num < t2h * fn2) {
            ssum.x += f.x; ssum.y += f.y; ssum.z += f.z; ssum.w += f.w;
            scnt += 1.f;
        }
    }
    ssum = red_es4(ssum);
    scnt = red_es(scnt);

    float4 a;
    if (scnt > 0.f) {
        float r = 1.f / scnt;
        a = make_float4(ssum.x * r, ssum.y * r, ssum.z * r, ssum.w * r);
    } else {
        a = hk;
    }
    if (es == 0) *(float4*)&agg[(size_t)wid * E_SIZE + q * 4] = a;
}

// ---------------- GEMM: out[N][128] = [h_in | agg] @ W^T ----------------
// BM=128, BN=128(all), BK=32; 256 threads; 8x8 acc per thread.

__global__ __launch_bounds__(256) void k_gemm(
    const float* __restrict__ A0,   // h_in [N][128]
    const float* __restrict__ A1,   // agg  [N][32]
    const float* __restrict__ W,    // [128][160]
    float* __restrict__ out, int N)
{
    __shared__ float As[128][33];   // +1 pad: a-reads conflict-free
    __shared__ float Bs[32][132];   // transposed W chunk; 132 keeps float4 rows 16B-aligned
    int t = threadIdx.x;
    int m0 = blockIdx.x * 128;
    int tn = t & 15, tm = t >> 4;
    float acc[8][8];
    #pragma unroll
    for (int r = 0; r < 8; ++r)
        #pragma unroll
        for (int c = 0; c < 8; ++c) acc[r][c] = 0.f;

    for (int chunk = 0; chunk < 5; ++chunk) {
        // stage A tile (rows m0..m0+127, k-cols chunk*32..+31)
        #pragma unroll
        for (int l = 0; l < 4; ++l) {
            int id = l * 256 + t;          // 0..1023 float4 slots
            int r = id >> 3;               // 0..127
            int qq = id & 7;               // float4 col within 32
            int m = m0 + r;
            float4 v = make_float4(0.f, 0.f, 0.f, 0.f);
            if (m < N) {
                if (chunk < 4) v = *(const float4*)&A0[(size_t)m * IN_SIZE + chunk * 32 + qq * 4];
                else           v = *(const float4*)&A1[(size_t)m * E_SIZE + qq * 4];
            }
            As[r][qq * 4 + 0] = v.x; As[r][qq * 4 + 1] = v.y;
            As[r][qq * 4 + 2] = v.z; As[r][qq * 4 + 3] = v.w;
        }
        // stage W chunk transposed: Bs[kk][h] = W[h][chunk*32+kk]
        {
            int h  = t >> 1;
            int kb = (t & 1) * 16;
            #pragma unroll
            for (int i2 = 0; i2 < 4; ++i2) {
                float4 v = *(const float4*)&W[(size_t)h * KDIM + chunk * 32 + kb + i2 * 4];
                int kkq = kb + i2 * 4;
                Bs[kkq + 0][h] = v.x; Bs[kkq + 1][h] = v.y;
                Bs[kkq + 2][h] = v.z; Bs[kkq + 3][h] = v.w;
            }
        }
        __syncthreads();
        #pragma unroll 4
        for (int kk = 0; kk < 32; ++kk) {
            float a[8], b[8];
            #pragma unroll
            for (int r = 0; r < 8; ++r) a[r] = As[tm * 8 + r][kk];
            float4 b0 = *(const float4*)&Bs[kk][tn * 8];
            float4 b1 = *(const float4*)&Bs[kk][tn * 8 + 4];
            b[0] = b0.x; b[1] = b0.y; b[2] = b0.z; b[3] = b0.w;
            b[4] = b1.x; b[5] = b1.y; b[6] = b1.z; b[7] = b1.w;
            #pragma unroll
            for (int r = 0; r < 8; ++r)
                #pragma unroll
                for (int c = 0; c < 8; ++c)
                    acc[r][c] = fmaf(a[r], b[c], acc[r][c]);
        }
        __syncthreads();
    }
    #pragma unroll
    for (int r = 0; r < 8; ++r) {
        int m = m0 + tm * 8 + r;
        if (m < N) {
            float4 o0 = make_float4(acc[r][0], acc[r][1], acc[r][2], acc[r][3]);
            float4 o1 = make_float4(acc[r][4], acc[r][5], acc[r][6], acc[r][7]);
            *(float4*)&out[(size_t)m * IN_SIZE + tn * 8]     = o0;
            *(float4*)&out[(size_t)m * IN_SIZE + tn * 8 + 4] = o1;
        }
    }
}

// ---------------- launch ----------------

extern "C" void kernel_launch(void* const* d_in, const int* in_sizes, int n_in,
                              void* d_out, int out_size, void* d_ws, size_t ws_size,
                              hipStream_t stream) {
    const float* h_in = (const float*)d_in[0];
    const float* ef   = (const float*)d_in[1];
    const int*   dst  = (const int*)d_in[2];
    const float* W    = (const float*)d_in[3];
    float* out = (float*)d_out;
    int N = in_sizes[0] / IN_SIZE;     // 50000
    int E = in_sizes[2];               // 1600000
    int nbk = (N + BNODES - 1) >> BSHIFT;   // 782 buckets (<= NBK_MAX)

    // workspace carve-out (256B aligned)
    char* p = (char*)d_ws;
    auto take = [&](size_t bytes) { char* r = p; p += (bytes + 255) & ~(size_t)255; return r; };
    int*   offsets = (int*)take((size_t)(N + 1) * 4);
    int*   bktcnt  = (int*)take((size_t)nbk * 4);
    int*   bktbase = (int*)take((size_t)(nbk + 1) * 4);
    int*   bcur    = (int*)take((size_t)nbk * 4);
    int*   binb    = (int*)take((size_t)E * 4);
    int*   eidsb   = (int*)take((size_t)E * 4);
    float* agg     = (float*)take((size_t)N * E_SIZE * 4);

    hipMemsetAsync(bktcnt, 0, (size_t)nbk * 4, stream);
    k_bhist  <<<NBIN_BLOCKS, 256, 0, stream>>>(dst, bktcnt, E, nbk);
    k_bscan  <<<1, 1024, 0, stream>>>(bktcnt, bktbase, bcur, nbk, offsets, N, E);
    k_bin_agg<<<NBIN_BLOCKS, 256, 0, stream>>>(dst, bcur, binb, E, nbk);
    k_fill3  <<<nbk, 256, 0, stream>>>(bktbase, binb, eidsb, offsets, N);
    k_node   <<<(N + 3) / 4, 256, 0, stream>>>(ef, offsets, eidsb, agg, N);
    k_gemm   <<<(N + 127) / 128, 256, 0, stream>>>(h_in, agg, W, out, N);
}

// Round 6
// 144.174 us; speedup vs baseline: 4.1856x; 1.0446x over previous
//
#include <hip/hip_runtime.h>
#include <math.h>

#define IN_SIZE 128
#define E_SIZE  32
#define KDIM    160
#define THRESH  0.5f
#define BSHIFT  6                    // 64 nodes per bucket
#define BNODES  (1 << BSHIFT)
#define NBK_MAX 1024                 // nbk = ceil(50000/64) = 782 <= 1024
#define NBIN_BLOCKS 256

// ---------------- bucket histogram (block-aggregated) ----------------

__global__ __launch_bounds__(256) void k_bhist(
    const int* __restrict__ dst, int* __restrict__ bktcnt, int E, int nbk)
{
    __shared__ int hist[NBK_MAX];
    int tid = threadIdx.x;
    for (int b = tid; b < nbk; b += 256) hist[b] = 0;
    __syncthreads();
    int chunk = (E + gridDim.x - 1) / gridDim.x;
    int s = blockIdx.x * chunk;
    int e = s + chunk; if (e > E) e = E;
    for (int i = s + tid; i < e; i += 256)
        atomicAdd(&hist[dst[i] >> BSHIFT], 1);
    __syncthreads();
    for (int b = tid; b < nbk; b += 256)
        if (hist[b]) atomicAdd(&bktcnt[b], hist[b]);
}

// ---------------- scan bucket totals -> bases + cursors ----------------

__global__ __launch_bounds__(1024) void k_bscan(
    const int* __restrict__ bktcnt, int* __restrict__ bktbase, int* __restrict__ bcur,
    int nbk, int* __restrict__ offsets, int N, int E)
{
    __shared__ int s[1024];
    int tid = threadIdx.x;
    int v = (tid < nbk) ? bktcnt[tid] : 0;
    s[tid] = v;
    __syncthreads();
    for (int off = 1; off < 1024; off <<= 1) {
        int add = (tid >= off) ? s[tid - off] : 0;
        __syncthreads();
        s[tid] += add;
        __syncthreads();
    }
    if (tid < nbk) {
        int base = s[tid] - v;          // exclusive
        bktbase[tid] = base;
        bcur[tid]    = base;
    }
    if (tid == 0) { bktbase[nbk] = E; offsets[N] = E; }
}

// ---------------- binning: block-aggregated counting sort ----------------
// bin entry packs (edge_id << 6) | (dst & 63); eid < 2^21 so it fits in 27 bits.

__global__ __launch_bounds__(256) void k_bin_agg(
    const int* __restrict__ dst, int* __restrict__ bcur,
    int* __restrict__ bin, int E, int nbk)
{
    __shared__ int hist[NBK_MAX];
    __shared__ int base[NBK_MAX];
    int tid = threadIdx.x;
    for (int b = tid; b < nbk; b += 256) hist[b] = 0;
    __syncthreads();
    int chunk = (E + gridDim.x - 1) / gridDim.x;
    int s = blockIdx.x * chunk;
    int e = s + chunk; if (e > E) e = E;
    for (int i = s + tid; i < e; i += 256)
        atomicAdd(&hist[dst[i] >> BSHIFT], 1);
    __syncthreads();
    for (int b = tid; b < nbk; b += 256) {
        int c = hist[b];
        base[b] = c ? atomicAdd(&bcur[b], c) : 0;   // reserve a contiguous run
        hist[b] = 0;                                // reuse as local cursor
    }
    __syncthreads();
    for (int i = s + tid; i < e; i += 256) {
        int d = dst[i];
        int b = d >> BSHIFT;
        int p = base[b] + atomicAdd(&hist[b], 1);
        bin[p] = (i << BSHIFT) | (d & (BNODES - 1));
    }
}

// ---------------- per-bucket exact placement + offsets ----------------
// one block per bucket; per-node counts/cursors in LDS; writes stay in one ~8KB region.

__global__ __launch_bounds__(256) void k_fill3(
    const int* __restrict__ bktbase, const int* __restrict__ bin,
    int* __restrict__ eids, int* __restrict__ offsets, int N)
{
    __shared__ int cnt[BNODES];
    __shared__ int nb0[BNODES];
    int b = blockIdx.x;
    int n0 = b << BSHIFT;
    int tid = threadIdx.x;
    int s = bktbase[b];
    int e = bktbase[b + 1];
    if (tid < BNODES) cnt[tid] = 0;
    __syncthreads();
    for (int k = s + tid; k < e; k += 256)
        atomicAdd(&cnt[bin[k] & (BNODES - 1)], 1);
    __syncthreads();
    if (tid < BNODES) {                         // wave 0: shuffle scan of 64 degs
        int v = cnt[tid];
        int x = v;
        #pragma unroll
        for (int off = 1; off < 64; off <<= 1) {
            int y = __shfl_up(x, off);
            if (tid >= off) x += y;
        }
        int nodebase = s + x - v;               // exclusive
        nb0[tid] = nodebase;
        if (n0 + tid < N) offsets[n0 + tid] = nodebase;
        cnt[tid] = 0;                           // reuse as cursor
    }
    __syncthreads();
    for (int k = s + tid; k < e; k += 256) {
        int pk = bin[k];
        int ln = pk & (BNODES - 1);
        int p = nb0[ln] + atomicAdd(&cnt[ln], 1);
        eids[p] = pk >> BSHIFT;
    }
}

// ---------------- per-node aggregate (1 wave / node, 8 edges x 8 float4-lanes) ----------------
// lane = es*8 + q : es = edge slot (0..7), q = feature quarter (owns features q*4..q*4+3).
// eids loaded coalesced (1 per lane) + shfl-distributed; edge rows register-cached across
// both phases (covers deg<=64; dynamic overflow loop beyond, ~never taken for this input).

__device__ __forceinline__ float red_q(float x) {        // sum across q (lane bits 0..2)
    x += __shfl_xor(x, 1); x += __shfl_xor(x, 2); x += __shfl_xor(x, 4);
    return x;
}
__device__ __forceinline__ float red_es(float x) {       // sum across es (lane bits 3..5)
    x += __shfl_xor(x, 8); x += __shfl_xor(x, 16); x += __shfl_xor(x, 32);
    return x;
}
__device__ __forceinline__ float4 red_es4(float4 v) {
    v.x = red_es(v.x); v.y = red_es(v.y); v.z = red_es(v.z); v.w = red_es(v.w);
    return v;
}

__global__ __launch_bounds__(256, 6) void k_node(
    const float* __restrict__ ef, const int* __restrict__ offsets,
    const int* __restrict__ eids, float* __restrict__ agg, int N)
{
    int wid = blockIdx.x * 4 + (threadIdx.x >> 6);   // node id
    if (wid >= N) return;
    int lane = threadIdx.x & 63;
    int es = lane >> 3;
    int q  = lane & 7;
    int start = offsets[wid];
    int deg   = offsets[wid + 1] - start;

    // one coalesced eid load per lane; distribute via shfl
    int myeid = (lane < deg) ? eids[start + lane] : 0;

    // preload up to 8 edge rows per slot into registers (static indices — stays in VGPRs)
    float4 fc[8];
    #pragma unroll
    for (int it = 0; it < 8; ++it) {
        int i = es + it * 8;
        int eid = __shfl(myeid, i);
        float4 f = make_float4(0.f, 0.f, 0.f, 0.f);
        if (i < deg)                        // uniform within each 8-lane q-group
            f = *(const float4*)&ef[(size_t)eid * E_SIZE + q * 4];
        fc[it] = f;
    }

    // phase A: per-feature sum over in-edges
    float4 esum = make_float4(0.f, 0.f, 0.f, 0.f);
    #pragma unroll
    for (int it = 0; it < 8; ++it) {
        esum.x += fc[it].x; esum.y += fc[it].y; esum.z += fc[it].z; esum.w += fc[it].w;
    }
    for (int i = es + 64; i < deg; i += 8) {            // overflow (deg>64): ~never
        int eid = eids[start + i];
        float4 f = *(const float4*)&ef[(size_t)eid * E_SIZE + q * 4];
        esum.x += f.x; esum.y += f.y; esum.z += f.z; esum.w += f.w;
    }
    esum = red_es4(esum);
    float inv = (deg > 0) ? 1.f / (float)deg : 0.f;
    float4 hk = make_float4(esum.x * inv, esum.y * inv, esum.z * inv, esum.w * inv);
    float hn2 = hk.x * hk.x + hk.y * hk.y + hk.z * hk.z + hk.w * hk.w;
    hn2 = red_q(hn2);                                   // ||hk||^2, all lanes
    float t2h = 0.25f * hn2;                            // THRESH^2 * ||hk||^2

    // phase B: cos < 0.5  <=>  num < 0  ||  num^2 < 0.25*hn2*fn2   (sqrt/div-free;
    // num=fn2=0 (inactive slot / zero row) -> excluded, matching jnp's NaN semantics)
    float4 ssum = make_float4(0.f, 0.f, 0.f, 0.f);
    float scnt = 0.f;
    #pragma unroll
    for (int it = 0; it < 8; ++it) {
        float4 f = fc[it];
        float num = hk.x * f.x + hk.y * f.y + hk.z * f.z + hk.w * f.w;
        float fn2 = f.x * f.x + f.y * f.y + f.z * f.z + f.w * f.w;
        num = red_q(num);
        fn2 = red_q(fn2);
        if (num < 0.f || num * num < t2h * fn2) {
            ssum.x += f.x; ssum.y += f.y; ssum.z += f.z; ssum.w += f.w;
            scnt += (es + it * 8 < deg) ? 1.f : 0.f;    // count real edges only (f=0 adds 0 to ssum)
        }
    }
    for (int i = es + 64; i < deg; i += 8) {            // overflow (deg>64): ~never
        int eid = eids[start + i];
        float4 f = *(const float4*)&ef[(size_t)eid * E_SIZE + q * 4];
        float num = hk.x * f.x + hk.y * f.y + hk.z * f.z + hk.w * f.w;
        float fn2 = f.x * f.x + f.y * f.y + f.z * f.z + f.w * f.w;
        num = red_q(num);
        fn2 = red_q(fn2);
        if (num < 0.f || num * num < t2h * fn2) {
            ssum.x += f.x; ssum.y += f.y; ssum.z += f.z; ssum.w += f.w;
            scnt += 1.f;
        }
    }
    ssum = red_es4(ssum);
    scnt = red_es(scnt);

    float4 a;
    if (scnt > 0.f) {
        float r = 1.f / scnt;
        a = make_float4(ssum.x * r, ssum.y * r, ssum.z * r, ssum.w * r);
    } else {
        a = hk;
    }
    if (es == 0) *(float4*)&agg[(size_t)wid * E_SIZE + q * 4] = a;
}

// ---------------- GEMM: out[N][128] = [h_in | agg] @ W^T ----------------
// BM=128, BN=64, BK=32; 782 blocks (fine-grained — kills the 391-block tail);
// 256 threads; 8x4 acc per thread.

__global__ __launch_bounds__(256) void k_gemm(
    const float* __restrict__ A0,   // h_in [N][128]
    const float* __restrict__ A1,   // agg  [N][32]
    const float* __restrict__ W,    // [128][160]
    float* __restrict__ out, int N)
{
    __shared__ float As[128][33];   // +1 pad: a-reads conflict-free
    __shared__ float Bs[32][68];    // transposed W half-chunk; stride 68 floats = 272B (16B-aligned)
    int t = threadIdx.x;
    int m0 = (blockIdx.x >> 1) * 128;
    int c0 = (blockIdx.x & 1) * 64;
    int tn = t & 15, tm = t >> 4;
    float acc[8][4];
    #pragma unroll
    for (int r = 0; r < 8; ++r)
        #pragma unroll
        for (int c = 0; c < 4; ++c) acc[r][c] = 0.f;

    int hl = t & 63;                // W-row within the 64-col half (lane-major: conflict-free writes)
    int kg = t >> 6;                // k-octet 0..3

    for (int chunk = 0; chunk < 5; ++chunk) {
        // stage A tile (rows m0..m0+127, k-cols chunk*32..+31)
        #pragma unroll
        for (int l = 0; l < 4; ++l) {
            int id = l * 256 + t;          // 0..1023 float4 slots
            int r = id >> 3;               // 0..127
            int qq = id & 7;               // float4 col within 32
            int m = m0 + r;
            float4 v = make_float4(0.f, 0.f, 0.f, 0.f);
            if (m < N) {
                if (chunk < 4) v = *(const float4*)&A0[(size_t)m * IN_SIZE + chunk * 32 + qq * 4];
                else           v = *(const float4*)&A1[(size_t)m * E_SIZE + qq * 4];
            }
            As[r][qq * 4 + 0] = v.x; As[r][qq * 4 + 1] = v.y;
            As[r][qq * 4 + 2] = v.z; As[r][qq * 4 + 3] = v.w;
        }
        // stage W half-chunk transposed: Bs[kk][hl] = W[c0+hl][chunk*32+kk] (W is L2-hot, 80KB)
        {
            const float* wrow = &W[(size_t)(c0 + hl) * KDIM + chunk * 32 + kg * 8];
            float4 v0 = *(const float4*)&wrow[0];
            float4 v1 = *(const float4*)&wrow[4];
            int k0 = kg * 8;
            Bs[k0 + 0][hl] = v0.x; Bs[k0 + 1][hl] = v0.y;
            Bs[k0 + 2][hl] = v0.z; Bs[k0 + 3][hl] = v0.w;
            Bs[k0 + 4][hl] = v1.x; Bs[k0 + 5][hl] = v1.y;
            Bs[k0 + 6][hl] = v1.z; Bs[k0 + 7][hl] = v1.w;
        }
        __syncthreads();
        #pragma unroll 4
        for (int kk = 0; kk < 32; ++kk) {
            float a[8];
            #pragma unroll
            for (int r = 0; r < 8; ++r) a[r] = As[tm * 8 + r][kk];
            float4 b = *(const float4*)&Bs[kk][tn * 4];
            #pragma unroll
            for (int r = 0; r < 8; ++r) {
                acc[r][0] = fmaf(a[r], b.x, acc[r][0]);
                acc[r][1] = fmaf(a[r], b.y, acc[r][1]);
                acc[r][2] = fmaf(a[r], b.z, acc[r][2]);
                acc[r][3] = fmaf(a[r], b.w, acc[r][3]);
            }
        }
        __syncthreads();
    }
    #pragma unroll
    for (int r = 0; r < 8; ++r) {
        int m = m0 + tm * 8 + r;
        if (m < N) {
            float4 o = make_float4(acc[r][0], acc[r][1], acc[r][2], acc[r][3]);
            *(float4*)&out[(size_t)m * IN_SIZE + c0 + tn * 4] = o;
        }
    }
}

// ---------------- launch ----------------

extern "C" void kernel_launch(void* const* d_in, const int* in_sizes, int n_in,
                              void* d_out, int out_size, void* d_ws, size_t ws_size,
                              hipStream_t stream) {
    const float* h_in = (const float*)d_in[0];
    const float* ef   = (const float*)d_in[1];
    const int*   dst  = (const int*)d_in[2];
    const float* W    = (const float*)d_in[3];
    float* out = (float*)d_out;
    int N = in_sizes[0] / IN_SIZE;     // 50000
    int E = in_sizes[2];               // 1600000
    int nbk = (N + BNODES - 1) >> BSHIFT;   // 782 buckets (<= NBK_MAX)

    // workspace carve-out (256B aligned)
    char* p = (char*)d_ws;
    auto take = [&](size_t bytes) { char* r = p; p += (bytes + 255) & ~(size_t)255; return r; };
    int*   offsets = (int*)take((size_t)(N + 1) * 4);
    int*   bktcnt  = (int*)take((size_t)nbk * 4);
    int*   bktbase = (int*)take((size_t)(nbk + 1) * 4);
    int*   bcur    = (int*)take((size_t)nbk * 4);
    int*   binb    = (int*)take((size_t)E * 4);
    int*   eidsb   = (int*)take((size_t)E * 4);
    float* agg     = (float*)take((size_t)N * E_SIZE * 4);

    hipMemsetAsync(bktcnt, 0, (size_t)nbk * 4, stream);
    k_bhist  <<<NBIN_BLOCKS, 256, 0, stream>>>(dst, bktcnt, E, nbk);
    k_bscan  <<<1, 1024, 0, stream>>>(bktcnt, bktbase, bcur, nbk, offsets, N, E);
    k_bin_agg<<<NBIN_BLOCKS, 256, 0, stream>>>(dst, bcur, binb, E, nbk);
    k_fill3  <<<nbk, 256, 0, stream>>>(bktbase, binb, eidsb, offsets, N);
    k_node   <<<(N + 3) / 4, 256, 0, stream>>>(ef, offsets, eidsb, agg, N);
    k_gemm   <<<((N + 127) / 128) * 2, 256, 0, stream>>>(h_in, agg, W, out, N);
}